// Round 4
// baseline (59.935 us; speedup 1.0000x reference)
//
#include <hip/hip_runtime.h>

#define COLS 4096
#define C4   (COLS / 4)
#define TROWS 4096
#define PAIRS (TROWS - 1)   // 4095

// ---------------------------------------------------------------------------
// Mergeable run record.
// Full form (32 B): head run (hs,hc), tail/open run (ts,tc), interior
// sum-of-means ms / count mc, ao = whole-span-is-one-open-run flag.
// Packed form (16 B): x=hs y=ts z=ms w=bits[ hc:10 | tc:10 | mc:10 | ao:2 ]
// (counts <= PCH <= 1023 guaranteed by NC >= 8 fallback).
// ---------------------------------------------------------------------------
struct Rec { float hs, hc, ts, tc, ms, mc, ao; };

__device__ inline Rec rec_merge(const Rec& L, const Rec& R) {
    Rec o;
    if (L.ao != 0.f && R.ao != 0.f) {
        o.hs = L.hs + R.hs; o.hc = L.hc + R.hc;
        o.ts = o.hs;        o.tc = o.hc;
        o.ms = 0.f; o.mc = 0.f; o.ao = 1.f;
    } else if (L.ao != 0.f) {
        o.hs = L.hs + R.hs; o.hc = L.hc + R.hc;   // L's run extends R's head
        o.ts = R.ts; o.tc = R.tc;
        o.ms = R.ms; o.mc = R.mc; o.ao = 0.f;
    } else if (R.ao != 0.f) {
        o.hs = L.hs; o.hc = L.hc;
        o.ts = L.ts + R.hs; o.tc = L.tc + R.hc;   // L's tail extends through R
        o.ms = L.ms; o.mc = L.mc; o.ao = 0.f;
    } else {
        o.hs = L.hs; o.hc = L.hc;
        o.ts = R.ts; o.tc = R.tc;
        float js = L.ts + R.hs, jc = L.tc + R.hc; // join run closes
        bool v = jc > 0.f;
        o.ms = L.ms + R.ms + (v ? js / jc : 0.f);
        o.mc = L.mc + R.mc + (v ? 1.f : 0.f);
        o.ao = 0.f;
    }
    return o;
}

__device__ inline Rec rec16_load(const float4* base, size_t idx) {
    float4 a = base[idx];
    unsigned u = __float_as_uint(a.w);
    Rec r;
    r.hs = a.x; r.ts = a.y; r.ms = a.z;
    r.hc = (float)(u & 1023u);
    r.tc = (float)((u >> 10) & 1023u);
    r.mc = (float)((u >> 20) & 1023u);
    r.ao = (float)(u >> 30);
    return r;
}

__device__ inline Rec rec32_load(const float4* base, size_t idx) {
    float4 a = base[idx * 2], b = base[idx * 2 + 1];
    Rec r; r.hs = a.x; r.hc = a.y; r.ts = a.z; r.tc = a.w;
    r.ms = b.x; r.mc = b.y; r.ao = b.z; return r;
}
__device__ inline void rec32_store(float4* base, size_t idx, const Rec& r) {
    base[idx * 2]     = make_float4(r.hs, r.hc, r.ts, r.tc);
    base[idx * 2 + 1] = make_float4(r.ms, r.mc, r.ao, 0.f);
}

// ---------------------------------------------------------------------------
// Phase 1: thread scans 4 adjacent columns over one chunk of pairs, explicit
// double-buffered 4-row batches. __launch_bounds__(256,4) -> 128 VGPR cap so
// both batch buffers (64 regs) + scan state actually fit and loads pipeline.
// Emits one packed 16 B record per column.
// ---------------------------------------------------------------------------
__global__ __launch_bounds__(256, 4)
void msi_phase1(const float4* __restrict__ p4, const int4* __restrict__ s4,
                float4* __restrict__ recs, int NC, int PCH) {
    int g = blockIdx.x * blockDim.x + threadIdx.x;   // column group (4 cols)
    int c = blockIdx.y;                              // chunk
    int t0 = c * PCH;
    int t1 = t0 + PCH; if (t1 > PAIRS) t1 = PAIRS;

    float4 pp = p4[(size_t)t0 * C4 + g];
    int4   sp = s4[(size_t)t0 * C4 + g];
    float pprev[4] = {pp.x, pp.y, pp.z, pp.w};
    int   sprev[4] = {sp.x, sp.y, sp.z, sp.w};

    float cs[4] = {0.f, 0.f, 0.f, 0.f};
    int   cc[4] = {0, 0, 0, 0};
    float hs[4] = {0.f, 0.f, 0.f, 0.f};
    int   hc[4] = {0, 0, 0, 0};
    int   hd[4] = {0, 0, 0, 0};
    float ms[4] = {0.f, 0.f, 0.f, 0.f};
    int   mc[4] = {0, 0, 0, 0};

#define PROC(PV, SV)                                                          \
    {                                                                         \
        float pcur[4] = {(PV).x, (PV).y, (PV).z, (PV).w};                     \
        int   scur[4] = {(SV).x, (SV).y, (SV).z, (SV).w};                     \
        _Pragma("unroll")                                                     \
        for (int k = 0; k < 4; ++k) {                                         \
            float d = pcur[k] - pprev[k];                                     \
            bool same = (scur[k] == sprev[k]);                                \
            bool first = !same && !hd[k];                                     \
            bool interior = !same && hd[k] && (cc[k] > 0);                    \
            hs[k] = first ? cs[k] : hs[k];                                    \
            hc[k] = first ? cc[k] : hc[k];                                    \
            float mean = cs[k] * __builtin_amdgcn_rcpf((float)cc[k]);         \
            ms[k] += interior ? mean : 0.f;                                   \
            mc[k] += interior ? 1 : 0;                                        \
            hd[k] = hd[k] | (same ? 0 : 1);                                   \
            cs[k] = same ? cs[k] + d * d : 0.f;                               \
            cc[k] = same ? cc[k] + 1 : 0;                                     \
            pprev[k] = pcur[k];                                               \
            sprev[k] = scur[k];                                               \
        }                                                                     \
    }

    int n = t1 - t0;
    int nb = n >> 2;
    size_t base = (size_t)(t0 + 1) * C4 + g;
    const size_t stride = 4 * (size_t)C4;

    if (nb > 0) {
        float4 P0 = p4[base], P1 = p4[base + C4], P2 = p4[base + 2 * C4], P3 = p4[base + 3 * C4];
        int4   S0 = s4[base], S1 = s4[base + C4], S2 = s4[base + 2 * C4], S3 = s4[base + 3 * C4];
        base += stride;
        #pragma unroll 2
        for (int b = 0; b < nb - 1; ++b) {
            float4 Q0 = p4[base], Q1 = p4[base + C4], Q2 = p4[base + 2 * C4], Q3 = p4[base + 3 * C4];
            int4   T0 = s4[base], T1 = s4[base + C4], T2 = s4[base + 2 * C4], T3 = s4[base + 3 * C4];
            base += stride;
            PROC(P0, S0); PROC(P1, S1); PROC(P2, S2); PROC(P3, S3);
            P0 = Q0; P1 = Q1; P2 = Q2; P3 = Q3;
            S0 = T0; S1 = T1; S2 = T2; S3 = T3;
        }
        PROC(P0, S0); PROC(P1, S1); PROC(P2, S2); PROC(P3, S3);
    }
    for (int t = t0 + (nb << 2); t < t1; ++t) {
        size_t bb = (size_t)(t + 1) * C4 + g;
        float4 P0 = p4[bb];
        int4   S0 = s4[bb];
        PROC(P0, S0);
    }
#undef PROC

    // Emit 4 packed 16 B records (64 B contiguous per thread).
    #pragma unroll
    for (int k = 0; k < 4; ++k) {
        int r = 4 * g + k;
        float4 a;
        if (!hd[k]) {
            unsigned u = (unsigned)cc[k] | ((unsigned)cc[k] << 10) | (3u << 30);
            a = make_float4(cs[k], cs[k], 0.f, __uint_as_float(u));
        } else {
            unsigned u = (unsigned)hc[k] | ((unsigned)cc[k] << 10) |
                         ((unsigned)mc[k] << 20);
            a = make_float4(hs[k], cs[k], ms[k], __uint_as_float(u));
        }
        recs[(size_t)c * COLS + r] = a;
    }
}

// ---------------------------------------------------------------------------
// Phase 2a: merge G consecutive chunk-records per column into a 32 B super.
// ---------------------------------------------------------------------------
__global__ void msi_phase2a(const float4* __restrict__ recs, float4* __restrict__ supers,
                            int G) {
    int r = blockIdx.x * blockDim.x + threadIdx.x;   // column
    int sup = blockIdx.y;
    size_t base = (size_t)sup * G * COLS + r;
    Rec acc = rec16_load(recs, base);
    #pragma unroll 4
    for (int j = 1; j < G; ++j) {
        Rec nxt = rec16_load(recs, base + (size_t)j * COLS);
        acc = rec_merge(acc, nxt);
    }
    rec32_store(supers, (size_t)sup * COLS + r, acc);
}

// ---------------------------------------------------------------------------
// Phase 2b: merge NSUP supers per column, finalize, block-reduce in double.
// ---------------------------------------------------------------------------
__global__ void msi_phase2b(const float4* __restrict__ supers, double* __restrict__ partials,
                            int NSUP) {
    int r = blockIdx.x * blockDim.x + threadIdx.x;
    Rec acc = rec32_load(supers, r);
    for (int j = 1; j < NSUP; ++j)
        acc = rec_merge(acc, rec32_load(supers, (size_t)j * COLS + r));

    double msum, mcnt;
    if (acc.ao != 0.f) {
        bool v = acc.hc > 0.f;
        msum = v ? (double)(acc.hs / acc.hc) : 0.0;
        mcnt = v ? 1.0 : 0.0;
    } else {
        msum = (double)acc.ms; mcnt = (double)acc.mc;
        if (acc.hc > 0.f) { msum += (double)(acc.hs / acc.hc); mcnt += 1.0; }
        if (acc.tc > 0.f) { msum += (double)(acc.ts / acc.tc); mcnt += 1.0; }
    }

    __shared__ double ls[256];
    __shared__ double lc[256];
    int tid = threadIdx.x;
    ls[tid] = msum; lc[tid] = mcnt;
    __syncthreads();
    for (int off = 128; off > 0; off >>= 1) {
        if (tid < off) { ls[tid] += ls[tid + off]; lc[tid] += lc[tid + off]; }
        __syncthreads();
    }
    if (tid == 0) {
        partials[blockIdx.x * 2 + 0] = ls[0];
        partials[blockIdx.x * 2 + 1] = lc[0];
    }
}

__global__ void msi_phase3(const double* __restrict__ partials, int nparts,
                           float* __restrict__ out) {
    int tid = threadIdx.x;
    double msum = 0.0, mcnt = 0.0;
    if (tid < nparts) {
        msum = partials[tid * 2 + 0];
        mcnt = partials[tid * 2 + 1];
    }
    for (int off = 32; off > 0; off >>= 1) {
        msum += __shfl_down(msum, off);
        mcnt += __shfl_down(mcnt, off);
    }
    if (tid == 0) out[0] = (mcnt > 0.0) ? (float)(msum / mcnt) : 0.f;
}

extern "C" void kernel_launch(void* const* d_in, const int* in_sizes, int n_in,
                              void* d_out, int out_size, void* d_ws, size_t ws_size,
                              hipStream_t stream) {
    const float4* p = (const float4*)d_in[0];
    const int4*   s = (const int4*)d_in[1];
    float* out = (float*)d_out;

    const int nblocks2 = COLS / 256;  // 16
    int NC = 256;
    auto need = [&](int nc) -> size_t {
        int gg = nc < 16 ? nc : 16;
        int nsup = nc / gg;
        return (size_t)nc * COLS * 16 + (size_t)nsup * COLS * 32 +
               (size_t)nblocks2 * 2 * sizeof(double);
    };
    while (NC > 8 && need(NC) > ws_size) NC >>= 1;
    int G = NC < 16 ? NC : 16;
    int NSUP = NC / G;
    int PCH = (PAIRS + NC - 1) / NC;

    float4* recs     = (float4*)d_ws;                        // NC*COLS 16B recs
    float4* supers   = recs + (size_t)NC * COLS;             // NSUP*COLS 32B recs
    double* partials = (double*)(supers + (size_t)NSUP * COLS * 2);

    dim3 g1(C4 / 256, NC);        // 4 x NC blocks of 256
    msi_phase1<<<g1, 256, 0, stream>>>(p, s, recs, NC, PCH);
    dim3 g2a(COLS / 256, NSUP);
    msi_phase2a<<<g2a, 256, 0, stream>>>(recs, supers, G);
    msi_phase2b<<<nblocks2, 256, 0, stream>>>(supers, partials, NSUP);
    msi_phase3<<<1, 64, 0, stream>>>(partials, nblocks2, out);
}